// Round 1
// baseline (180.589 us; speedup 1.0000x reference)
//
#include <hip/hip_runtime.h>
#include <math.h>

#define B_  2048
#define N_  4096
#define D_  1024
#define NEGG 4093   // negatives per group = N - 2 - K (K=1)

typedef _Float16 f16;
typedef unsigned long long u64;
typedef __attribute__((ext_vector_type(8))) _Float16 f16x8;
typedef __attribute__((ext_vector_type(4))) float     f32x4;

#define AS1 __attribute__((address_space(1)))
#define AS3 __attribute__((address_space(3)))

__device__ __forceinline__ void gload_lds16(const void* g, void* l) {
    __builtin_amdgcn_global_load_lds((const AS1 void*)g, (AS3 void*)l, 16, 0, 0);
}

// ---------------------------------------------------------------------------
// Kernel 0: split h=[h_i;h_j] (fp32) into fp16 hi/lo pair; block 0 zeroes
// out[0] (group's atomic target runs two kernels later, same stream).
// ---------------------------------------------------------------------------
struct alignas(8) h4 { f16 a, b, c, d; };

__global__ __launch_bounds__(256)
void split_kernel(const float* __restrict__ a, const float* __restrict__ b,
                  f16* __restrict__ ph, f16* __restrict__ pl,
                  float* __restrict__ out)
{
    if (blockIdx.x == 0 && threadIdx.x == 0) out[0] = 0.0f;
    size_t t   = (size_t)blockIdx.x * 256 + threadIdx.x;
    size_t off = t * 4;                       // 4 floats per thread
    const size_t half = (size_t)B_ * D_;
    const float* src = (off < half) ? (a + off) : (b + (off - half));
    float4 v = *reinterpret_cast<const float4*>(src);
    f16 h0 = (f16)v.x, h1 = (f16)v.y, h2 = (f16)v.z, h3 = (f16)v.w;
    f16 l0 = (f16)(v.x - (float)h0);
    f16 l1 = (f16)(v.y - (float)h1);
    f16 l2 = (f16)(v.z - (float)h2);
    f16 l3 = (f16)(v.w - (float)h3);
    *reinterpret_cast<h4*>(ph + off) = {h0, h1, h2, h3};
    *reinterpret_cast<h4*>(pl + off) = {l0, l1, l2, l3};
}

// ---------------------------------------------------------------------------
// Kernel 1: sim = 2*(Hh Hh^T + Hh Hl^T + Hl Hh^T) via MFMA 16x16x32 f16.
// Phased schedule (T3+T4+T5 port to 128^2): BK=32, h|l packed in 128-B LDS
// rows (chunks 0-3 = k-hi, 4-7 = k-lo; phys chunk = logical ^ (row&7) —
// same conflict-free geometry as the previous kernel, measured 0 conflicts).
// Double-buffered 2x(A,B) panels = 64 KB -> still 2 blocks/CU.
// 4 phases per K-tile, one output quadrant (12 MFMA) each; frag reads
// 8/4/4/0 per phase with register reuse; prefetch of tile t+1 issued at
// phases 0-1 (4+4 gload_lds), drained by a single vmcnt(0) at phase 3
// (2-3 phases of slack -> loads retired, no per-step full drain).
// Diagonal 128^2 tiles are 32 extra full-tile blocks (grid 528): mirror
// writes of a symmetric tile are bitwise identical, so dup stores are safe.
// ---------------------------------------------------------------------------
__global__ __launch_bounds__(256)
void gemm_kernel(const f16* __restrict__ Hh, const f16* __restrict__ Hl,
                 float* __restrict__ sim)
{
    __shared__ __align__(16) f16 lds[2][2][128 * 64];   // [buf][A/B][row*64+chunk*8]

    const int tid  = threadIdx.x;
    const int wave = tid >> 6;
    const int lane = tid & 63;

    int idx = blockIdx.x;
    int by, bx;
    if (idx < 496) {
        by = (int)((sqrtf(8.0f * (float)idx + 1.0f) + 1.0f) * 0.5f);
        while (by * (by - 1) / 2 > idx) --by;
        while ((by + 1) * by / 2 <= idx) ++by;
        bx = idx - by * (by - 1) / 2;
    } else {
        by = bx = idx - 496;                 // diagonal tile, full 128x128
    }
    const int m0 = by * 128;
    const int n0 = bx * 128;

    const int wm   = (wave >> 1) * 64;
    const int wn   = (wave & 1) * 64;
    const int l15  = lane & 15;
    const int quad = lane >> 4;
    const int r7   = l15 & 7;
    const int cH   = (quad ^ r7) * 8;        // phys byte-chunk for k-hi frag
    const int cL   = ((4 | quad) ^ r7) * 8;  // phys byte-chunk for k-lo frag

    // row offsets (in f16) into a panel for this lane's fragment rows
    int ra[4], rb[4];
#pragma unroll
    for (int m = 0; m < 4; ++m) ra[m] = (wm + m * 16 + l15) * 64;
#pragma unroll
    for (int n = 0; n < 4; ++n) rb[n] = (wn + n * 16 + l15) * 64;

    // staging role: waves 0,1 -> A panel halves; waves 2,3 -> B panel halves
    const int sp    = wave >> 1;             // 0 = A, 1 = B
    const int rbase = (wave & 1) * 64;
    const int lr8   = lane >> 3;             // row within 8-row stripe
    const int logc  = (lane & 7) ^ lr8;      // logical chunk 0..7 (swizzled src)
    const f16* smat = (logc < 4) ? Hh : Hl;
    const f16* gsrc = smat
                    + (size_t)((sp ? n0 : m0) + rbase + lr8) * D_
                    + (size_t)(logc & 3) * 8;
    f16* st0 = &lds[0][sp][rbase * 64];
    f16* st1 = &lds[1][sp][rbase * 64];

    const f16* aB0 = &lds[0][0][0]; const f16* aB1 = &lds[1][0][0];
    const f16* bB0 = &lds[0][1][0]; const f16* bB1 = &lds[1][1][0];

    f32x4 acc[4][4];
#pragma unroll
    for (int i = 0; i < 4; i++)
#pragma unroll
        for (int j = 0; j < 4; j++) { acc[i][j][0]=0.f; acc[i][j][1]=0.f; acc[i][j][2]=0.f; acc[i][j][3]=0.f; }

    f16x8 a0h[2], a0l[2], a1h[2], a1l[2];
    f16x8 b0h[2], b0l[2], b1h[2], b1l[2];

    // -------- prologue: stage K-tile 0 into buf 0 --------
#pragma unroll
    for (int s = 0; s < 8; ++s)
        gload_lds16(gsrc + (size_t)s * 8 * D_, st0 + s * 512);
    asm volatile("s_waitcnt vmcnt(0)" ::: "memory");
    __builtin_amdgcn_s_barrier();

#pragma unroll 2
    for (int t = 0; t < 32; ++t) {
        const int cur = t & 1;
        const f16* A  = cur ? aB1 : aB0;
        const f16* Bp = cur ? bB1 : bB0;
        f16* dstb     = cur ? st0 : st1;     // stage tile t+1 into other buf
        const size_t koff = (size_t)(t + 1) * 32;
        const bool pf = (t < 31);

        // ================= phase 0: quadrant (mt 0-1) x (nt 0-1) ============
#pragma unroll
        for (int i = 0; i < 2; ++i) {
            a0h[i] = *reinterpret_cast<const f16x8*>(A + ra[i] + cH);
            a0l[i] = *reinterpret_cast<const f16x8*>(A + ra[i] + cL);
        }
#pragma unroll
        for (int j = 0; j < 2; ++j) {
            b0h[j] = *reinterpret_cast<const f16x8*>(Bp + rb[j] + cH);
            b0l[j] = *reinterpret_cast<const f16x8*>(Bp + rb[j] + cL);
        }
        if (pf) {
#pragma unroll
            for (int s = 0; s < 4; ++s)
                gload_lds16(gsrc + koff + (size_t)s * 8 * D_, dstb + s * 512);
        }
        __builtin_amdgcn_s_barrier();
        asm volatile("s_waitcnt lgkmcnt(0)" ::: "memory");
        __builtin_amdgcn_sched_barrier(0);
        __builtin_amdgcn_s_setprio(1);
#pragma unroll
        for (int i = 0; i < 2; ++i)
#pragma unroll
            for (int j = 0; j < 2; ++j) {
                acc[i][j] = __builtin_amdgcn_mfma_f32_16x16x32_f16(a0h[i], b0h[j], acc[i][j], 0, 0, 0);
                acc[i][j] = __builtin_amdgcn_mfma_f32_16x16x32_f16(a0h[i], b0l[j], acc[i][j], 0, 0, 0);
                acc[i][j] = __builtin_amdgcn_mfma_f32_16x16x32_f16(a0l[i], b0h[j], acc[i][j], 0, 0, 0);
            }
        __builtin_amdgcn_s_setprio(0);
        __builtin_amdgcn_s_barrier();

        // ================= phase 1: quadrant (mt 2-3) x (nt 0-1) ============
#pragma unroll
        for (int i = 0; i < 2; ++i) {
            a1h[i] = *reinterpret_cast<const f16x8*>(A + ra[2 + i] + cH);
            a1l[i] = *reinterpret_cast<const f16x8*>(A + ra[2 + i] + cL);
        }
        if (pf) {
#pragma unroll
            for (int s = 4; s < 8; ++s)
                gload_lds16(gsrc + koff + (size_t)s * 8 * D_, dstb + s * 512);
        }
        __builtin_amdgcn_s_barrier();
        asm volatile("s_waitcnt lgkmcnt(0)" ::: "memory");
        __builtin_amdgcn_sched_barrier(0);
        __builtin_amdgcn_s_setprio(1);
#pragma unroll
        for (int i = 0; i < 2; ++i)
#pragma unroll
            for (int j = 0; j < 2; ++j) {
                acc[2+i][j] = __builtin_amdgcn_mfma_f32_16x16x32_f16(a1h[i], b0h[j], acc[2+i][j], 0, 0, 0);
                acc[2+i][j] = __builtin_amdgcn_mfma_f32_16x16x32_f16(a1h[i], b0l[j], acc[2+i][j], 0, 0, 0);
                acc[2+i][j] = __builtin_amdgcn_mfma_f32_16x16x32_f16(a1l[i], b0h[j], acc[2+i][j], 0, 0, 0);
            }
        __builtin_amdgcn_s_setprio(0);
        __builtin_amdgcn_s_barrier();

        // ================= phase 2: quadrant (mt 2-3) x (nt 2-3) ============
#pragma unroll
        for (int j = 0; j < 2; ++j) {
            b1h[j] = *reinterpret_cast<const f16x8*>(Bp + rb[2 + j] + cH);
            b1l[j] = *reinterpret_cast<const f16x8*>(Bp + rb[2 + j] + cL);
        }
        __builtin_amdgcn_s_barrier();
        asm volatile("s_waitcnt lgkmcnt(0)" ::: "memory");
        __builtin_amdgcn_sched_barrier(0);
        __builtin_amdgcn_s_setprio(1);
#pragma unroll
        for (int i = 0; i < 2; ++i)
#pragma unroll
            for (int j = 0; j < 2; ++j) {
                acc[2+i][2+j] = __builtin_amdgcn_mfma_f32_16x16x32_f16(a1h[i], b1h[j], acc[2+i][2+j], 0, 0, 0);
                acc[2+i][2+j] = __builtin_amdgcn_mfma_f32_16x16x32_f16(a1h[i], b1l[j], acc[2+i][2+j], 0, 0, 0);
                acc[2+i][2+j] = __builtin_amdgcn_mfma_f32_16x16x32_f16(a1l[i], b1h[j], acc[2+i][2+j], 0, 0, 0);
            }
        __builtin_amdgcn_s_setprio(0);
        __builtin_amdgcn_s_barrier();

        // ========= phase 3: quadrant (mt 0-1) x (nt 2-3), reg reuse =========
        __builtin_amdgcn_s_setprio(1);
#pragma unroll
        for (int i = 0; i < 2; ++i)
#pragma unroll
            for (int j = 0; j < 2; ++j) {
                acc[i][2+j] = __builtin_amdgcn_mfma_f32_16x16x32_f16(a0h[i], b1h[j], acc[i][2+j], 0, 0, 0);
                acc[i][2+j] = __builtin_amdgcn_mfma_f32_16x16x32_f16(a0h[i], b1l[j], acc[i][2+j], 0, 0, 0);
                acc[i][2+j] = __builtin_amdgcn_mfma_f32_16x16x32_f16(a0l[i], b1h[j], acc[i][2+j], 0, 0, 0);
            }
        __builtin_amdgcn_s_setprio(0);
        // drain this wave's prefetch of tile t+1 (issued 2-3 phases ago);
        // barrier then guarantees every wave's staging is complete before
        // any wave reads the new buffer at the next phase 0.
        asm volatile("s_waitcnt vmcnt(0)" ::: "memory");
        __builtin_amdgcn_s_barrier();
    }

    // -------- epilogue: direct + mirrored writes (x2 for temperature) -------
#pragma unroll
    for (int mt = 0; mt < 4; ++mt) {
        int r = m0 + wm + mt * 16 + quad * 4;
#pragma unroll
        for (int nt = 0; nt < 4; ++nt) {
            int c = n0 + wn + nt * 16 + l15;
#pragma unroll
            for (int reg = 0; reg < 4; ++reg)
                sim[(size_t)(r + reg) * N_ + c] = 2.0f * acc[mt][nt][reg];
        }
    }
#pragma unroll
    for (int mt = 0; mt < 4; ++mt) {
        int cb = m0 + wm + mt * 16 + quad * 4;
#pragma unroll
        for (int nt = 0; nt < 4; ++nt) {
            int rr = n0 + wn + nt * 16 + l15;
            float4 v = { 2.0f * acc[mt][nt][0], 2.0f * acc[mt][nt][1],
                         2.0f * acc[mt][nt][2], 2.0f * acc[mt][nt][3] };
            *reinterpret_cast<float4*>(&sim[(size_t)rr * N_ + cb]) = v;
        }
    }
}

// ---------------------------------------------------------------------------
// Kernel 2: per-anchor top-4, BRANCH-FREE (round-8 exact: 2048 blocks).
// u64 key (mono(val)<<32)|(4095-j) == jax.lax.top_k stable order.
// ---------------------------------------------------------------------------
__device__ __forceinline__ u64 mkkey(float v, int j) {
    unsigned u = __float_as_uint(v);
    u = (u & 0x80000000u) ? ~u : (u | 0x80000000u);   // monotonic float map
    return ((u64)u << 32) | (unsigned)(4095 - j);
}

__device__ __forceinline__ void kins(u64& k0, u64& k1, u64& k2, u64& k3, u64 key) {
    u64 lo = key, t;
    t = (k0 > lo) ? k0 : lo; lo = (k0 > lo) ? lo : k0; k0 = t;
    t = (k1 > lo) ? k1 : lo; lo = (k1 > lo) ? lo : k1; k1 = t;
    t = (k2 > lo) ? k2 : lo; lo = (k2 > lo) ? lo : k2; k2 = t;
    k3 = (k3 > lo) ? k3 : lo;
}

__global__ __launch_bounds__(256)
void topk_kernel(const float* __restrict__ sim, int* __restrict__ e,
                 int* __restrict__ ex)
{
    const int i   = blockIdx.x;      // anchor
    const int tid = threadIdx.x;
    const float* rowA = sim + (size_t)i * N_ + B_;        // sim[i, B+j]
    const float* rowB = sim + (size_t)(B_ + i) * N_;      // sim[B+i, j]

    u64 k0 = 0, k1 = 0, k2 = 0, k3 = 0;   // 0 < every real key
#pragma unroll
    for (int it = 0; it < 4; ++it) {
        int base = tid * 4 + it * 1024;
        float4 v4 = (base < B_) ? *reinterpret_cast<const float4*>(rowA + base)
                                : *reinterpret_cast<const float4*>(rowB + (base - B_));
        float vals[4] = { v4.x, v4.y, v4.z, v4.w };
#pragma unroll
        for (int u = 0; u < 4; ++u)
            kins(k0, k1, k2, k3, mkkey(vals[u], base + u));
    }

    __shared__ u64 lk[1024];
    lk[tid * 4 + 0] = k0; lk[tid * 4 + 1] = k1;
    lk[tid * 4 + 2] = k2; lk[tid * 4 + 3] = k3;
    __syncthreads();

    if (tid < 64) {
#pragma unroll
        for (int w = 1; w < 4; ++w) {
            int th = tid + w * 64;
#pragma unroll
            for (int s = 0; s < 4; ++s)
                kins(k0, k1, k2, k3, lk[th * 4 + s]);
        }
        u64 M[4];
#pragma unroll
        for (int r = 0; r < 4; ++r) {
            u64 mx = k0;
#pragma unroll
            for (int off = 32; off >= 1; off >>= 1) {
                u64 o = __shfl_xor(mx, off);
                mx = (mx > o) ? mx : o;
            }
            M[r] = mx;
            if (k0 == mx) { k0 = k1; k1 = k2; k2 = k3; k3 = 0; }  // keys unique
        }
        if (tid == 0) {
            int topi[4];
#pragma unroll
            for (int r = 0; r < 4; ++r)
                topi[r] = 4095 - (int)(unsigned)(M[r] & 0xFFFFFFFFull);
            int exi[2] = {0x7fffffff, 0x7fffffff}; int ei = 0;
            int exb[2] = {0x7fffffff, 0x7fffffff}; int eb = 0;
            int taken = 0;
#pragma unroll
            for (int t = 0; t < 4; ++t) {
                if (taken >= 2) break;
                int idxj = topi[t];
                if (idxj == i || idxj == i + B_) continue;   // anchor pair: invalid
                ++taken;
                if (idxj < B_) exi[ei++] = B_ + idxj;        // row i, col B+idx
                else           exb[eb++] = idxj - B_;        // row B+i, col idx-B
            }
            if (ei == 2 && exi[0] > exi[1]) { int t = exi[0]; exi[0] = exi[1]; exi[1] = t; }
            if (eb == 2 && exb[0] > exb[1]) { int t = exb[0]; exb[0] = exb[1]; exb[1] = t; }
            e[i] = ei;        ex[2*i]        = exi[0]; ex[2*i+1]        = exi[1];
            e[B_ + i] = eb;   ex[2*(B_+i)]   = exb[0]; ex[2*(B_+i)+1]   = exb[1];
        }
    }
}

// ---------------------------------------------------------------------------
// Kernel 3: per-group LSE, one wave per group, single memory pass; E scan
// computed in-block from e. negatives(g) = flat range [F0,F1) minus <=12
// point exclusions; static 17-quad sweep -> 68 register-resident values;
// butterfly max; register exps; butterfly add; one atomicAdd per block.
// ---------------------------------------------------------------------------
__global__ __launch_bounds__(256)
void group_kernel(const float* __restrict__ sim, const int* __restrict__ e,
                  const int* __restrict__ ex, float* __restrict__ out)
{
    const int tid  = threadIdx.x;
    const int wave = tid >> 6;
    const int lane = tid & 63;
    const int g    = blockIdx.x * 4 + wave;
    __shared__ int   sE[4097];
    __shared__ int   partial[256];
    __shared__ float posv[4][2];
    __shared__ int   exf[4][12];
    __shared__ int   fF0[4], fF1[4];
    __shared__ float wgl[4];

    // ---- in-block exclusive prefix scan of e -> sE ----
    {
        const int base0 = tid * 16;
        int loc[16];
        int s = 0;
#pragma unroll
        for (int q = 0; q < 16; q += 4) {
            int4 ev = *reinterpret_cast<const int4*>(e + base0 + q);
            loc[q+0] = s; s += ev.x;
            loc[q+1] = s; s += ev.y;
            loc[q+2] = s; s += ev.z;
            loc[q+3] = s; s += ev.w;
        }
        partial[tid] = s;
        __syncthreads();
        for (int off = 1; off < 256; off <<= 1) {
            int tmp = (tid >= off) ? partial[tid - off] : 0;
            __syncthreads();
            partial[tid] += tmp;
            __syncthreads();
        }
        int excl = partial[tid] - s;
#pragma unroll
        for (int q = 0; q < 16; q++) sE[base0 + q] = excl + loc[q];
        if (tid == 255) sE[4096] = partial[255];
    }
    __syncthreads();

    // ---- per-wave setup: lanes 0,1 -> positives; lane 2 -> flat range ----
    if (lane < 2) {
        int p = 2 * g + lane;
        int lo = 0, hi = N_ - 1;
        while (lo < hi) {
            int mid = (lo + hi + 1) >> 1;
            if (mid + sE[mid] <= p) lo = mid; else hi = mid - 1;
        }
        int r = lo;
        int q = p - (r + sE[r]);
        int pr = (r < B_) ? r + B_ : r - B_;
        int a0 = ex[2*r], a1 = ex[2*r+1];
        int p0 = pr, p1 = a0, p2 = a1;               // sort3 (sentinels last)
        if (p0 > p1) { int tm = p0; p0 = p1; p1 = tm; }
        if (p1 > p2) { int tm = p1; p1 = p2; p2 = tm; }
        if (p0 > p1) { int tm = p0; p0 = p1; p1 = tm; }
        int c = (q == 0) ? p0 : ((q == 1) ? p1 : p2);
        posv[wave][lane] = sim[(size_t)r * N_ + c];
    } else if (lane == 2) {
        long long s0 = (long long)NEGG * g;
        long long s1 = s0 + NEGG;
        int lo = 0, hi = N_ - 1;
        while (lo < hi) {
            int mid = (lo + hi + 1) >> 1;
            long long Q = 4094LL * mid - sE[mid];
            if (Q <= s0) lo = mid; else hi = mid - 1;
        }
        int lR[3], lCa[3], lCb[3], lX[3][4];
        int np = 0;
        long long s = s0;
        int r = lo;
        while (s < s1 && np < 3) {
            long long Qr = 4094LL * r - sE[r];
            int er = sE[r+1] - sE[r];
            int nr = 4094 - er;
            long long ka = s - Qr;
            long long kb = s1 - Qr; if (kb > nr) kb = nr;
            int X[4];
            X[0] = (r < B_) ? r : r - B_;
            X[1] = (r < B_) ? r + B_ : r;
            X[2] = ex[2*r]; X[3] = ex[2*r+1];
            if (X[0] > X[1]) { int t = X[0]; X[0] = X[1]; X[1] = t; }
            if (X[2] > X[3]) { int t = X[2]; X[2] = X[3]; X[3] = t; }
            if (X[0] > X[2]) { int t = X[0]; X[0] = X[2]; X[2] = t; }
            if (X[1] > X[3]) { int t = X[1]; X[1] = X[3]; X[3] = t; }
            if (X[1] > X[2]) { int t = X[1]; X[1] = X[2]; X[2] = t; }
            int ca = (int)ka;
#pragma unroll
            for (int t = 0; t < 4; t++) if (X[t] <= ca) ca++;
            int cb = (int)kb - 1;
#pragma unroll
            for (int t = 0; t < 4; t++) if (X[t] <= cb) cb++;
            cb += 1;
            lR[np] = r; lCa[np] = ca; lCb[np] = cb;
#pragma unroll
            for (int t = 0; t < 4; t++) lX[np][t] = X[t];
            ++np;
            s += (kb - ka);
            r += 1;
        }
        int F0 = lR[0] * N_ + lCa[0];
        int F1 = lR[np-1] * N_ + lCb[np-1];
        fF0[wave] = F0; fF1[wave] = F1;
#pragma unroll
        for (int pz = 0; pz < 3; ++pz)
#pragma unroll
            for (int t = 0; t < 4; ++t) {
                int fx = -1;
                if (pz < np && lX[pz][t] < N_) {
                    int cand = lR[pz] * N_ + lX[pz][t];
                    if (cand >= F0 && cand < F1) fx = cand;
                }
                exf[wave][pz * 4 + t] = fx;
            }
    }
    __syncthreads();

    const int F0 = fF0[wave], F1 = fF1[wave];
    int exr[12];
#pragma unroll
    for (int t = 0; t < 12; ++t) exr[t] = exf[wave][t];
    const int base4 = F0 & ~3;

    // ---- single pass: load + mask into registers, track max ----
    float v[17][4];
    float lm = -3.0e38f;
#pragma unroll
    for (int it = 0; it < 17; ++it) {
        int c4 = base4 + (it * 64 + lane) * 4;
        int c4s = (c4 > N_ * N_ - 4) ? (N_ * N_ - 4) : c4;
        float4 q = *reinterpret_cast<const float4*>(sim + c4s);
        float vals[4] = { q.x, q.y, q.z, q.w };
#pragma unroll
        for (int u = 0; u < 4; ++u) {
            int f = c4 + u;
            bool keep = (f >= F0) & (f < F1);
#pragma unroll
            for (int t = 0; t < 12; ++t) keep &= (f != exr[t]);
            float val = keep ? vals[u] : -INFINITY;
            v[it][u] = val;
            lm = fmaxf(lm, val);
        }
    }
#pragma unroll
    for (int off = 32; off >= 1; off >>= 1)
        lm = fmaxf(lm, __shfl_xor(lm, off));

    float ls = 0.f;
#pragma unroll
    for (int it = 0; it < 17; ++it)
#pragma unroll
        for (int u = 0; u < 4; ++u)
            ls += __expf(v[it][u] - lm);          // exp(-inf)=0 for masked
#pragma unroll
    for (int off = 32; off >= 1; off >>= 1)
        ls += __shfl_xor(ls, off);

    if (lane == 0) {
        float q0 = posv[wave][0], q1 = posv[wave][1];
        float nm = fmaxf(lm, fmaxf(q0, q1));
        float stot = ls * __expf(lm - nm) + __expf(q0 - nm) + __expf(q1 - nm);
        wgl[wave] = (nm + __logf(stot)) - q0;
    }
    __syncthreads();
    if (tid == 0) {
        float gl = wgl[0] + wgl[1] + wgl[2] + wgl[3];
        atomicAdd(out, gl * (1.0f / 4096.0f));
    }
}

// ---------------------------------------------------------------------------
extern "C" void kernel_launch(void* const* d_in, const int* in_sizes, int n_in,
                              void* d_out, int out_size, void* d_ws, size_t ws_size,
                              hipStream_t stream)
{
    const float* hi = (const float*)d_in[0];
    const float* hj = (const float*)d_in[1];
    char* ws = (char*)d_ws;
    size_t off = 0;
    float* sim = (float*)(ws + off); off += (size_t)N_ * N_ * sizeof(float);  // 64 MB
    f16*   Hh  = (f16*)(ws + off);   off += (size_t)N_ * D_ * sizeof(f16);    // 8 MB
    f16*   Hl  = (f16*)(ws + off);   off += (size_t)N_ * D_ * sizeof(f16);    // 8 MB
    int*   e   = (int*)(ws + off);   off += 4096 * sizeof(int);
    int*   ex  = (int*)(ws + off);   off += 8192 * sizeof(int);

    split_kernel<<<(N_ * D_ / 4 + 255) / 256, 256, 0, stream>>>(hi, hj, Hh, Hl, (float*)d_out);
    const int nblocks = 496 + 32;   // strict lower-tri tiles + 32 full diagonal tiles
    gemm_kernel<<<nblocks, 256, 0, stream>>>(Hh, Hl, sim);
    topk_kernel<<<B_, 256, 0, stream>>>(sim, e, ex);
    group_kernel<<<N_ / 4, 256, 0, stream>>>(sim, e, ex, (float*)d_out);
}

// Round 2
// 155.265 us; speedup vs baseline: 1.1631x; 1.1631x over previous
//
#include <hip/hip_runtime.h>
#include <math.h>

#define B_  2048
#define N_  4096
#define D_  1024
#define NEGG 4093   // negatives per group = N - 2 - K (K=1)

typedef _Float16 f16;
typedef unsigned long long u64;
typedef __attribute__((ext_vector_type(8))) _Float16 f16x8;
typedef __attribute__((ext_vector_type(4))) float     f32x4;

#define AS1 __attribute__((address_space(1)))
#define AS3 __attribute__((address_space(3)))

__device__ __forceinline__ void gload_lds16(const void* g, void* l) {
    __builtin_amdgcn_global_load_lds((const AS1 void*)g, (AS3 void*)l, 16, 0, 0);
}

// ---------------------------------------------------------------------------
// Kernel 0: split h=[h_i;h_j] (fp32) into fp16 hi/lo pair; block 0 zeroes
// out[0] (group's atomic target runs two kernels later, same stream).
// ---------------------------------------------------------------------------
struct alignas(8) h4 { f16 a, b, c, d; };

__global__ __launch_bounds__(256)
void split_kernel(const float* __restrict__ a, const float* __restrict__ b,
                  f16* __restrict__ ph, f16* __restrict__ pl,
                  float* __restrict__ out)
{
    if (blockIdx.x == 0 && threadIdx.x == 0) out[0] = 0.0f;
    size_t t   = (size_t)blockIdx.x * 256 + threadIdx.x;
    size_t off = t * 4;                       // 4 floats per thread
    const size_t half = (size_t)B_ * D_;
    const float* src = (off < half) ? (a + off) : (b + (off - half));
    float4 v = *reinterpret_cast<const float4*>(src);
    f16 h0 = (f16)v.x, h1 = (f16)v.y, h2 = (f16)v.z, h3 = (f16)v.w;
    f16 l0 = (f16)(v.x - (float)h0);
    f16 l1 = (f16)(v.y - (float)h1);
    f16 l2 = (f16)(v.z - (float)h2);
    f16 l3 = (f16)(v.w - (float)h3);
    *reinterpret_cast<h4*>(ph + off) = {h0, h1, h2, h3};
    *reinterpret_cast<h4*>(pl + off) = {l0, l1, l2, l3};
}

// ---------------------------------------------------------------------------
// Kernel 1: sim = 2*(Hh Hh^T + Hh Hl^T + Hl Hh^T) via MFMA 16x16x32 f16.
// 496 strict-lower-tri 128x128 tiles; diag subtiles dealt s%31; mirrors.
// BK=64: 64 KB LDS (still 2 blocks/CU). Swizzle: phys_chunk = c ^ (row&7)
// -> 2 lanes per bank group on ds_read_b128 = conflict-free (m136).
// NOTE (round-1 post-mortem): the 4-phase counted-vmcnt schedule REGRESSED
// this kernel 57.5 -> 85 us (confirms learn_hip m232: 8-phase does not
// reproduce at 128^2/4-wave). This 2-barrier structure at ~900 TF is the
// ceiling for this tile size; implicit 2-block/CU overlap does the
// pipelining. Do not re-attempt source-level pipelining here.
// ---------------------------------------------------------------------------
__global__ __launch_bounds__(256)
void gemm_kernel(const f16* __restrict__ Hh, const f16* __restrict__ Hl,
                 float* __restrict__ sim)
{
    __shared__ __align__(16) f16 lds[4][128 * 64];   // 4 x 16 KB = 64 KB
    const int tid  = threadIdx.x;
    const int wave = tid >> 6;
    const int lane = tid & 63;

    int idx = blockIdx.x;
    int by = (int)((sqrtf(8.0f * (float)idx + 1.0f) + 1.0f) * 0.5f);
    while (by * (by - 1) / 2 > idx) --by;
    while ((by + 1) * by / 2 <= idx) ++by;
    int bx = idx - by * (by - 1) / 2;
    const int m0 = by * 128;
    const int n0 = bx * 128;

    int xs = -1, xpanel = 0, xb = 0;
    {
        int cnt = 0;
        for (int s = bx; s < 36; s += 31, ++cnt)
            if (cnt == wave) { xs = s; xpanel = 0; xb = by; }
        for (int s = by - 1; s < 36; s += 31, ++cnt)
            if (cnt == wave) { xs = s; xpanel = 2; xb = bx; }
    }
    int xmt = 0, xnt = 0;
    if (xs >= 0) {
        while ((xmt + 1) * (xmt + 2) / 2 <= xs) ++xmt;
        xnt = xs - xmt * (xmt + 1) / 2;
    }

    const int wm = (wave >> 1) * 64;
    const int wn = (wave & 1) * 64;
    const int l15  = lane & 15;
    const int quad = lane >> 4;

    f32x4 acc[4][4];
#pragma unroll
    for (int i = 0; i < 4; i++)
#pragma unroll
        for (int j = 0; j < 4; j++) { acc[i][j][0]=0.f; acc[i][j][1]=0.f; acc[i][j][2]=0.f; acc[i][j][3]=0.f; }
    f32x4 xacc; xacc[0]=0.f; xacc[1]=0.f; xacc[2]=0.f; xacc[3]=0.f;

    // staging (BK=64): lane -> row lane>>3 (8 rows/instr), chunk lane&7;
    // fetch swizzled global chunk so LDS[r][c] = A[r][(c ^ (r&7))*8 ..]
    const int lr8 = lane >> 3;
    const f16* gsrc = ((wave & 1) ? Hl : Hh)
                    + (size_t)((wave & 2) ? n0 : m0) * D_
                    + (size_t)lr8 * D_ + (size_t)(((lane & 7) ^ lr8) * 8);

    const int r7 = l15 & 7;                     // row&7 for all fragment rows

    for (int k0 = 0; k0 < D_; k0 += 64) {
#pragma unroll
        for (int s = 0; s < 16; ++s) {
            const f16* gp = gsrc + (size_t)(s * 8) * D_ + k0;
            gload_lds16(gp, &lds[wave][s * 512]);   // 8 rows x 64 f16 per instr
        }
        __syncthreads();

#pragma unroll
        for (int ks = 0; ks < 2; ++ks) {
            const int qc = (((ks << 2) | quad) ^ r7) * 8;
            f16x8 ah[4], al[4], bh[4], bl[4];
#pragma unroll
            for (int mt = 0; mt < 4; ++mt) {
                int row = wm + mt * 16 + l15;
                ah[mt] = *reinterpret_cast<const f16x8*>(&lds[0][row * 64 + qc]);
                al[mt] = *reinterpret_cast<const f16x8*>(&lds[1][row * 64 + qc]);
            }
#pragma unroll
            for (int nt = 0; nt < 4; ++nt) {
                int row = wn + nt * 16 + l15;
                bh[nt] = *reinterpret_cast<const f16x8*>(&lds[2][row * 64 + qc]);
                bl[nt] = *reinterpret_cast<const f16x8*>(&lds[3][row * 64 + qc]);
            }
#pragma unroll
            for (int mt = 0; mt < 4; ++mt)
#pragma unroll
                for (int nt = 0; nt < 4; ++nt) {
                    acc[mt][nt] = __builtin_amdgcn_mfma_f32_16x16x32_f16(ah[mt], bh[nt], acc[mt][nt], 0, 0, 0);
                    acc[mt][nt] = __builtin_amdgcn_mfma_f32_16x16x32_f16(ah[mt], bl[nt], acc[mt][nt], 0, 0, 0);
                    acc[mt][nt] = __builtin_amdgcn_mfma_f32_16x16x32_f16(al[mt], bh[nt], acc[mt][nt], 0, 0, 0);
                }
            if (xs >= 0) {
                f16x8 xah = *reinterpret_cast<const f16x8*>(&lds[xpanel    ][(xmt * 16 + l15) * 64 + qc]);
                f16x8 xal = *reinterpret_cast<const f16x8*>(&lds[xpanel + 1][(xmt * 16 + l15) * 64 + qc]);
                f16x8 xbh = *reinterpret_cast<const f16x8*>(&lds[xpanel    ][(xnt * 16 + l15) * 64 + qc]);
                f16x8 xbl = *reinterpret_cast<const f16x8*>(&lds[xpanel + 1][(xnt * 16 + l15) * 64 + qc]);
                xacc = __builtin_amdgcn_mfma_f32_16x16x32_f16(xah, xbh, xacc, 0, 0, 0);
                xacc = __builtin_amdgcn_mfma_f32_16x16x32_f16(xah, xbl, xacc, 0, 0, 0);
                xacc = __builtin_amdgcn_mfma_f32_16x16x32_f16(xal, xbh, xacc, 0, 0, 0);
            }
        }
        __syncthreads();
    }

#pragma unroll
    for (int mt = 0; mt < 4; ++mt) {
        int r = m0 + wm + mt * 16 + quad * 4;
#pragma unroll
        for (int nt = 0; nt < 4; ++nt) {
            int c = n0 + wn + nt * 16 + l15;
#pragma unroll
            for (int reg = 0; reg < 4; ++reg)
                sim[(size_t)(r + reg) * N_ + c] = 2.0f * acc[mt][nt][reg];
        }
    }
#pragma unroll
    for (int mt = 0; mt < 4; ++mt) {
        int cb = m0 + wm + mt * 16 + quad * 4;
#pragma unroll
        for (int nt = 0; nt < 4; ++nt) {
            int rr = n0 + wn + nt * 16 + l15;
            float4 v = { 2.0f * acc[mt][nt][0], 2.0f * acc[mt][nt][1],
                         2.0f * acc[mt][nt][2], 2.0f * acc[mt][nt][3] };
            *reinterpret_cast<float4*>(&sim[(size_t)rr * N_ + cb]) = v;
        }
    }
    if (xs >= 0) {
        int rb = xb * 128 + xmt * 16 + quad * 4;
        int cc = xb * 128 + xnt * 16 + l15;
#pragma unroll
        for (int reg = 0; reg < 4; ++reg)
            sim[(size_t)(rb + reg) * N_ + cc] = 2.0f * xacc[reg];
        if (xmt != xnt) {
            int rr = xb * 128 + xnt * 16 + l15;
            int cb = xb * 128 + xmt * 16 + quad * 4;
            float4 v = { 2.0f * xacc[0], 2.0f * xacc[1], 2.0f * xacc[2], 2.0f * xacc[3] };
            *reinterpret_cast<float4*>(&sim[(size_t)rr * N_ + cb]) = v;
        }
    }
}

// ---------------------------------------------------------------------------
// Kernel 2: per-anchor top-4, BRANCH-FREE (round-8 exact: 2048 blocks).
// u64 key (mono(val)<<32)|(4095-j) == jax.lax.top_k stable order.
// ---------------------------------------------------------------------------
__device__ __forceinline__ u64 mkkey(float v, int j) {
    unsigned u = __float_as_uint(v);
    u = (u & 0x80000000u) ? ~u : (u | 0x80000000u);   // monotonic float map
    return ((u64)u << 32) | (unsigned)(4095 - j);
}

__device__ __forceinline__ void kins(u64& k0, u64& k1, u64& k2, u64& k3, u64 key) {
    u64 lo = key, t;
    t = (k0 > lo) ? k0 : lo; lo = (k0 > lo) ? lo : k0; k0 = t;
    t = (k1 > lo) ? k1 : lo; lo = (k1 > lo) ? lo : k1; k1 = t;
    t = (k2 > lo) ? k2 : lo; lo = (k2 > lo) ? lo : k2; k2 = t;
    k3 = (k3 > lo) ? k3 : lo;
}

__global__ __launch_bounds__(256)
void topk_kernel(const float* __restrict__ sim, int* __restrict__ e,
                 int* __restrict__ ex)
{
    const int i   = blockIdx.x;      // anchor
    const int tid = threadIdx.x;
    const float* rowA = sim + (size_t)i * N_ + B_;        // sim[i, B+j]
    const float* rowB = sim + (size_t)(B_ + i) * N_;      // sim[B+i, j]

    u64 k0 = 0, k1 = 0, k2 = 0, k3 = 0;   // 0 < every real key
#pragma unroll
    for (int it = 0; it < 4; ++it) {
        int base = tid * 4 + it * 1024;
        float4 v4 = (base < B_) ? *reinterpret_cast<const float4*>(rowA + base)
                                : *reinterpret_cast<const float4*>(rowB + (base - B_));
        float vals[4] = { v4.x, v4.y, v4.z, v4.w };
#pragma unroll
        for (int u = 0; u < 4; ++u)
            kins(k0, k1, k2, k3, mkkey(vals[u], base + u));
    }

    __shared__ u64 lk[1024];
    lk[tid * 4 + 0] = k0; lk[tid * 4 + 1] = k1;
    lk[tid * 4 + 2] = k2; lk[tid * 4 + 3] = k3;
    __syncthreads();

    if (tid < 64) {
#pragma unroll
        for (int w = 1; w < 4; ++w) {
            int th = tid + w * 64;
#pragma unroll
            for (int s = 0; s < 4; ++s)
                kins(k0, k1, k2, k3, lk[th * 4 + s]);
        }
        u64 M[4];
#pragma unroll
        for (int r = 0; r < 4; ++r) {
            u64 mx = k0;
#pragma unroll
            for (int off = 32; off >= 1; off >>= 1) {
                u64 o = __shfl_xor(mx, off);
                mx = (mx > o) ? mx : o;
            }
            M[r] = mx;
            if (k0 == mx) { k0 = k1; k1 = k2; k2 = k3; k3 = 0; }  // keys unique
        }
        if (tid == 0) {
            int topi[4];
#pragma unroll
            for (int r = 0; r < 4; ++r)
                topi[r] = 4095 - (int)(unsigned)(M[r] & 0xFFFFFFFFull);
            int exi[2] = {0x7fffffff, 0x7fffffff}; int ei = 0;
            int exb[2] = {0x7fffffff, 0x7fffffff}; int eb = 0;
            int taken = 0;
#pragma unroll
            for (int t = 0; t < 4; ++t) {
                if (taken >= 2) break;
                int idxj = topi[t];
                if (idxj == i || idxj == i + B_) continue;   // anchor pair: invalid
                ++taken;
                if (idxj < B_) exi[ei++] = B_ + idxj;        // row i, col B+idx
                else           exb[eb++] = idxj - B_;        // row B+i, col idx-B
            }
            if (ei == 2 && exi[0] > exi[1]) { int t = exi[0]; exi[0] = exi[1]; exi[1] = t; }
            if (eb == 2 && exb[0] > exb[1]) { int t = exb[0]; exb[0] = exb[1]; exb[1] = t; }
            e[i] = ei;        ex[2*i]        = exi[0]; ex[2*i+1]        = exi[1];
            e[B_ + i] = eb;   ex[2*(B_+i)]   = exb[0]; ex[2*(B_+i)+1]   = exb[1];
        }
    }
}

// ---------------------------------------------------------------------------
// Kernel 3: per-group LSE, one wave per group, single memory pass.
// Round-2 changes (bit-identical results):
//  - e-scan: shuffle-based wave scan + 1 barrier (was Hillis-Steele w/ 16).
//  - exclusion mask: per-lane 68-bit kill bitmap built once (<=12 exclusions
//    each map to exactly one (lane,it,u) slot) -> hot loop mask is a static
//    shift+and instead of 12 compares per element (~1600 -> ~200 inst/lane).
// ---------------------------------------------------------------------------
__global__ __launch_bounds__(256)
void group_kernel(const float* __restrict__ sim, const int* __restrict__ e,
                  const int* __restrict__ ex, float* __restrict__ out)
{
    const int tid  = threadIdx.x;
    const int wave = tid >> 6;
    const int lane = tid & 63;
    const int g    = blockIdx.x * 4 + wave;
    __shared__ int   sE[4097];
    __shared__ int   wsum[4];
    __shared__ float posv[4][2];
    __shared__ int   exf[4][12];
    __shared__ int   fF0[4], fF1[4];
    __shared__ float wgl[4];

    // ---- in-block exclusive prefix scan of e -> sE (shuffle-based) ----
    {
        const int base0 = tid * 16;
        int loc[16];
        int s = 0;
#pragma unroll
        for (int q = 0; q < 16; q += 4) {
            int4 ev = *reinterpret_cast<const int4*>(e + base0 + q);
            loc[q+0] = s; s += ev.x;
            loc[q+1] = s; s += ev.y;
            loc[q+2] = s; s += ev.z;
            loc[q+3] = s; s += ev.w;
        }
        // inclusive wave scan of per-thread totals
        int scan = s;
#pragma unroll
        for (int off = 1; off <= 32; off <<= 1) {
            int t = __shfl_up(scan, off);
            if (lane >= off) scan += t;
        }
        if (lane == 63) wsum[wave] = scan;    // wave total
        __syncthreads();
        int wbase = 0;
#pragma unroll
        for (int w = 0; w < 4; ++w) wbase += (w < wave) ? wsum[w] : 0;
        int excl = wbase + scan - s;          // exclusive prefix for this thread
#pragma unroll
        for (int q = 0; q < 16; q++) sE[base0 + q] = excl + loc[q];
        if (tid == 255) sE[4096] = wbase + scan;
    }
    __syncthreads();

    // ---- per-wave setup: lanes 0,1 -> positives; lane 2 -> flat range ----
    if (lane < 2) {
        int p = 2 * g + lane;
        int lo = 0, hi = N_ - 1;
        while (lo < hi) {
            int mid = (lo + hi + 1) >> 1;
            if (mid + sE[mid] <= p) lo = mid; else hi = mid - 1;
        }
        int r = lo;
        int q = p - (r + sE[r]);
        int pr = (r < B_) ? r + B_ : r - B_;
        int a0 = ex[2*r], a1 = ex[2*r+1];
        int p0 = pr, p1 = a0, p2 = a1;               // sort3 (sentinels last)
        if (p0 > p1) { int tm = p0; p0 = p1; p1 = tm; }
        if (p1 > p2) { int tm = p1; p1 = p2; p2 = tm; }
        if (p0 > p1) { int tm = p0; p0 = p1; p1 = tm; }
        int c = (q == 0) ? p0 : ((q == 1) ? p1 : p2);
        posv[wave][lane] = sim[(size_t)r * N_ + c];
    } else if (lane == 2) {
        long long s0 = (long long)NEGG * g;
        long long s1 = s0 + NEGG;
        int lo = 0, hi = N_ - 1;
        while (lo < hi) {
            int mid = (lo + hi + 1) >> 1;
            long long Q = 4094LL * mid - sE[mid];
            if (Q <= s0) lo = mid; else hi = mid - 1;
        }
        int lR[3], lCa[3], lCb[3], lX[3][4];
        int np = 0;
        long long s = s0;
        int r = lo;
        while (s < s1 && np < 3) {
            long long Qr = 4094LL * r - sE[r];
            int er = sE[r+1] - sE[r];
            int nr = 4094 - er;
            long long ka = s - Qr;
            long long kb = s1 - Qr; if (kb > nr) kb = nr;
            int X[4];
            X[0] = (r < B_) ? r : r - B_;
            X[1] = (r < B_) ? r + B_ : r;
            X[2] = ex[2*r]; X[3] = ex[2*r+1];
            if (X[0] > X[1]) { int t = X[0]; X[0] = X[1]; X[1] = t; }
            if (X[2] > X[3]) { int t = X[2]; X[2] = X[3]; X[3] = t; }
            if (X[0] > X[2]) { int t = X[0]; X[0] = X[2]; X[2] = t; }
            if (X[1] > X[3]) { int t = X[1]; X[1] = X[3]; X[3] = t; }
            if (X[1] > X[2]) { int t = X[1]; X[1] = X[2]; X[2] = t; }
            int ca = (int)ka;
#pragma unroll
            for (int t = 0; t < 4; t++) if (X[t] <= ca) ca++;
            int cb = (int)kb - 1;
#pragma unroll
            for (int t = 0; t < 4; t++) if (X[t] <= cb) cb++;
            cb += 1;
            lR[np] = r; lCa[np] = ca; lCb[np] = cb;
#pragma unroll
            for (int t = 0; t < 4; t++) lX[np][t] = X[t];
            ++np;
            s += (kb - ka);
            r += 1;
        }
        int F0 = lR[0] * N_ + lCa[0];
        int F1 = lR[np-1] * N_ + lCb[np-1];
        fF0[wave] = F0; fF1[wave] = F1;
#pragma unroll
        for (int pz = 0; pz < 3; ++pz)
#pragma unroll
            for (int t = 0; t < 4; ++t) {
                int fx = -1;
                if (pz < np && lX[pz][t] < N_) {
                    int cand = lR[pz] * N_ + lX[pz][t];
                    if (cand >= F0 && cand < F1) fx = cand;
                }
                exf[wave][pz * 4 + t] = fx;
            }
    }
    __syncthreads();

    const int F0 = fF0[wave], F1 = fF1[wave];
    const int base4 = F0 & ~3;

    // ---- per-lane kill bitmap: bit (it*4+u) set if this lane's element
    // (it,u) is an excluded flat index. rel < 4352 so it <= 16 -> 68 bits.
    u64 kill0 = 0, kill1 = 0;
#pragma unroll
    for (int t = 0; t < 12; ++t) {
        int x = exf[wave][t];
        if (x >= 0) {
            int rel = x - base4;                       // >= 0 since x >= F0
            if (((rel >> 2) & 63) == lane) {
                int bit = (rel >> 8) * 4 + (rel & 3);  // it*4+u in [0,68)
                if (bit < 64) kill0 |= (1ull << bit);
                else          kill1 |= (1ull << (bit - 64));
            }
        }
    }

    // ---- single pass: load + mask into registers, track max ----
    float v[17][4];
    float lm = -3.0e38f;
#pragma unroll
    for (int it = 0; it < 17; ++it) {
        int c4 = base4 + (it * 64 + lane) * 4;
        int c4s = (c4 > N_ * N_ - 4) ? (N_ * N_ - 4) : c4;
        float4 q = *reinterpret_cast<const float4*>(sim + c4s);
        float vals[4] = { q.x, q.y, q.z, q.w };
#pragma unroll
        for (int u = 0; u < 4; ++u) {
            int f = c4 + u;
            bool range = (f >= F0) & (f < F1);
            unsigned kb = (it < 16) ? (unsigned)((kill0 >> (it * 4 + u)) & 1ull)
                                    : (unsigned)((kill1 >> u) & 1ull);
            bool keep = range & (kb == 0u);
            float val = keep ? vals[u] : -INFINITY;
            v[it][u] = val;
            lm = fmaxf(lm, val);
        }
    }
#pragma unroll
    for (int off = 32; off >= 1; off >>= 1)
        lm = fmaxf(lm, __shfl_xor(lm, off));

    float ls = 0.f;
#pragma unroll
    for (int it = 0; it < 17; ++it)
#pragma unroll
        for (int u = 0; u < 4; ++u)
            ls += __expf(v[it][u] - lm);          // exp(-inf)=0 for masked
#pragma unroll
    for (int off = 32; off >= 1; off >>= 1)
        ls += __shfl_xor(ls, off);

    if (lane == 0) {
        float q0 = posv[wave][0], q1 = posv[wave][1];
        float nm = fmaxf(lm, fmaxf(q0, q1));
        float stot = ls * __expf(lm - nm) + __expf(q0 - nm) + __expf(q1 - nm);
        wgl[wave] = (nm + __logf(stot)) - q0;
    }
    __syncthreads();
    if (tid == 0) {
        float gl = wgl[0] + wgl[1] + wgl[2] + wgl[3];
        atomicAdd(out, gl * (1.0f / 4096.0f));
    }
}

// ---------------------------------------------------------------------------
extern "C" void kernel_launch(void* const* d_in, const int* in_sizes, int n_in,
                              void* d_out, int out_size, void* d_ws, size_t ws_size,
                              hipStream_t stream)
{
    const float* hi = (const float*)d_in[0];
    const float* hj = (const float*)d_in[1];
    char* ws = (char*)d_ws;
    size_t off = 0;
    float* sim = (float*)(ws + off); off += (size_t)N_ * N_ * sizeof(float);  // 64 MB
    f16*   Hh  = (f16*)(ws + off);   off += (size_t)N_ * D_ * sizeof(f16);    // 8 MB
    f16*   Hl  = (f16*)(ws + off);   off += (size_t)N_ * D_ * sizeof(f16);    // 8 MB
    int*   e   = (int*)(ws + off);   off += 4096 * sizeof(int);
    int*   ex  = (int*)(ws + off);   off += 8192 * sizeof(int);

    split_kernel<<<(N_ * D_ / 4 + 255) / 256, 256, 0, stream>>>(hi, hj, Hh, Hl, (float*)d_out);
    const int nblocks = (N_ / 128) * (N_ / 128 - 1) / 2;   // 496 strict lower-tri
    gemm_kernel<<<nblocks, 256, 0, stream>>>(Hh, Hl, sim);
    topk_kernel<<<B_, 256, 0, stream>>>(sim, e, ex);
    group_kernel<<<N_ / 4, 256, 0, stream>>>(sim, e, ex, (float*)d_out);
}